// Round 5
// baseline (57.360 us; speedup 1.0000x reference)
//
#include <hip/hip_runtime.h>
#include <math.h>

#define N 512
#define D 256
#define ITILE 2
#define NPAIRS 261632.0f  // 512*511

typedef unsigned long long u64;
// bijective LDS index swizzle: spreads bitonic strides over all 16 b64
// bank-pairs (bits[3:0] ^= bits[7:4]); must be applied on EVERY q access.
#define SW(x) ((x) ^ (((x) >> 4) & 15))

__constant__ float kRad2Deg = 57.29577951308232f; // 180/pi

// ---------------------------------------------------------------------------
// Kernel 1: per-row prep. Block = one row i (512 blocks, 64 lanes).
// Lanes: ||f[i]||^2 via float4 + wave reduce. Lane 0: pose 6d->rot (det-
// normalized) + tvec, and block 0 zeroes the accumulator.
// ---------------------------------------------------------------------------
__global__ __launch_bounds__(64) void prep_kernel(
        const float* __restrict__ f,
        const float* __restrict__ labels,
        float* __restrict__ rot,
        float* __restrict__ tvec,
        float* __restrict__ nrm,
        float* __restrict__ acc) {
    const int i = blockIdx.x;
    const int l = threadIdx.x;

    const float4 v = ((const float4*)(f + i * D))[l];   // 64 lanes x 4 = 256
    float ss = v.x * v.x + v.y * v.y + v.z * v.z + v.w * v.w;
#pragma unroll
    for (int off = 32; off > 0; off >>= 1) ss += __shfl_down(ss, off, 64);

    if (l == 0) {
        nrm[i] = ss;
        const float* p = labels + i * 9;
        float a1x = p[0], a1y = p[1], a1z = p[2];
        float a2x = p[3], a2y = p[4], a2z = p[5];
        float n1 = sqrtf(a1x * a1x + a1y * a1y + a1z * a1z);
        float b1x = a1x / n1, b1y = a1y / n1, b1z = a1z / n1;
        float dp = b1x * a2x + b1y * a2y + b1z * a2z;
        float cx = a2x - dp * b1x, cy = a2y - dp * b1y, cz = a2z - dp * b1z;
        float n2 = sqrtf(cx * cx + cy * cy + cz * cz);
        float b2x = cx / n2, b2y = cy / n2, b2z = cz / n2;
        float b3x = b1y * b2z - b1z * b2y;
        float b3y = b1z * b2x - b1x * b2z;
        float b3z = b1x * b2y - b1y * b2x;
        float det = b1x * (b2y * b3z - b2z * b3y)
                  - b1y * (b2x * b3z - b2z * b3x)
                  + b1z * (b2x * b3y - b2y * b3x);
        float inv = 1.0f / cbrtf(det);
        float* r = rot + i * 9;
        r[0] = b1x * inv; r[1] = b1y * inv; r[2] = b1z * inv;
        r[3] = b2x * inv; r[4] = b2y * inv; r[5] = b2z * inv;
        r[6] = b3x * inv; r[7] = b3y * inv; r[8] = b3z * inv;
        tvec[i * 3 + 0] = p[6];
        tvec[i * 3 + 1] = p[7];
        tvec[i * 3 + 2] = p[8];
        if (i == 0) acc[0] = 0.0f;
    }
}

// ---------------------------------------------------------------------------
// Kernel 2: row data E/TD/SD via DOT-FORM distances:
//   d2(i,j) = nrm[i] + nrm[j] - 2 * f_i . f_j   (pure FMA inner loop).
// No cancellation risk (nrm ~ 256, dot ~ +-16). j==i is special-cased
// (dot-form d2_ii != exact 0): L=0, E=0 to match the reference exactly.
// ---------------------------------------------------------------------------
__global__ __launch_bounds__(512) void rowdata_kernel(
        const float* __restrict__ f,
        const float* __restrict__ rot,
        const float* __restrict__ tvec,
        const float* __restrict__ nrm,
        float* __restrict__ E,
        float* __restrict__ TD,
        float* __restrict__ SD,
        float* __restrict__ acc) {
    __shared__ __attribute__((aligned(16))) float lds_fi[ITILE * D];
    __shared__ float red[8];

    const int j  = threadIdx.x;          // column, 0..511
    const int i0 = blockIdx.x * ITILE;

    lds_fi[j] = f[i0 * D + j];           // 512 threads == ITILE*D floats
    __syncthreads();

    float dot0 = 0.0f, dot1 = 0.0f;
    const float4* __restrict__ fj4 = (const float4*)(f + j * D);
#pragma unroll 16
    for (int kk = 0; kk < D / 4; ++kk) {
        const float4 v = fj4[kk];
        const float4 a = *(const float4*)&lds_fi[kk * 4];
        const float4 b = *(const float4*)&lds_fi[D + kk * 4];
        dot0 += a.x * v.x; dot0 += a.y * v.y; dot0 += a.z * v.z; dot0 += a.w * v.w;
        dot1 += b.x * v.x; dot1 += b.y * v.y; dot1 += b.z * v.z; dot1 += b.w * v.w;
    }
    const float nj  = nrm[j];
    const float dotr[2] = { dot0, dot1 };

    float rj[9];
#pragma unroll
    for (int c = 0; c < 9; ++c) rj[c] = rot[j * 9 + c];
    const float tjx = tvec[j * 3 + 0];
    const float tjy = tvec[j * 3 + 1];
    const float tjz = tvec[j * 3 + 2];

    float lsum = 0.0f;
#pragma unroll
    for (int r = 0; r < ITILE; ++r) {
        const int i = i0 + r;
        float tr = 0.0f;
#pragma unroll
        for (int c = 0; c < 9; ++c) tr += rot[i * 9 + c] * rj[c];  // uniform i
        float ct = (tr - 1.0f) * 0.5f;
        ct = fminf(1.0f, fmaxf(-1.0f, ct));
        float theta = acosf(ct) * kRad2Deg;

        float dx = tvec[i * 3 + 0] - tjx;
        float dy = tvec[i * 3 + 1] - tjy;
        float dz = tvec[i * 3 + 2] - tjz;
        float sd2 = dx * dx + dy * dy + dz * dz;
        float shift = (sd2 > 0.0f ? sqrtf(sd2) : 0.0f) * 100.0f;

        float d2 = nrm[i] + nj - 2.0f * dotr[r];
        float L, Ev;
        if (j == i) { L = 0.0f; Ev = 0.0f; }                 // exact reference vals
        else {
            float dist = (d2 > 0.0f ? sqrtf(d2) : 0.0f);
            L  = -dist * 0.5f;        // TEMPERATURE=2; rowmax==0 (provable no-op)
            Ev = expf(L);
        }
        E[i * N + j]  = Ev;
        TD[i * N + j] = theta;
        SD[i * N + j] = shift;
        lsum += L;
    }

#pragma unroll
    for (int off = 32; off > 0; off >>= 1) lsum += __shfl_down(lsum, off, 64);
    const int lane = j & 63, wid = j >> 6;
    if (lane == 0) red[wid] = lsum;
    __syncthreads();
    if (j == 0) {
        float s = 0.0f;
#pragma unroll
        for (int w = 0; w < 8; ++w) s += red[w];
        atomicAdd(acc, s);
    }
}

// ---------------------------------------------------------------------------
// Kernel 3: sort-based denominators. Block = one row i, 256 threads.
// PACKED bitonic: element = (keybits<<32)|E_bits in one LDS u64, XOR-swizzled
// (SW) for bank-pair spread. One CE = 2x ds_read_b64 + u64 cmp + cond 2x
// ds_write_b64 (~half the LDS instrs of split key/payload). u64 tie-break by
// E-bits only permutes equal-key runs -> lb/suffix-sum semantics unchanged.
// Keys TD,SD >= 0 so float-bit order == value order.
// ---------------------------------------------------------------------------
__global__ __launch_bounds__(256) void sortdenom_kernel(
        const float* __restrict__ E,
        const float* __restrict__ TD,
        const float* __restrict__ SD,
        float* __restrict__ acc) {
    __shared__ u64   qT[512], qS[512];      // packed (key<<32)|E, swizzled
    __shared__ float sT[512], sS[512];      // suffix sums (unpacked E)
    __shared__ int   lT[512], lS[512];      // tie-run-start (lb) max-scan
    __shared__ float redA[4], redB[4];
    __shared__ float diag_part_sh;

    const int t = threadIdx.x;
    const int i = blockIdx.x;
    const float* __restrict__ er = E  + i * N;
    const float* __restrict__ tr = TD + i * N;
    const float* __restrict__ sr = SD + i * N;

    const float e0 = er[t], e1 = er[t + 256];
    const float t0 = tr[t], t1 = tr[t + 256];
    const float s0 = sr[t], s1 = sr[t + 256];
    const float dT = tr[i], dS = sr[i];     // diagonal thresholds

    // ---- direct diag denominators (the excluded j==i terms) ----
    float dtd = ((t0 >= dT) ? e0 : 0.0f) + ((t1 >= dT) ? e1 : 0.0f);
    float dsd = ((s0 >= dS) ? e0 : 0.0f) + ((s1 >= dS) ? e1 : 0.0f);
#pragma unroll
    for (int off = 32; off > 0; off >>= 1) {
        dtd += __shfl_down(dtd, off, 64);
        dsd += __shfl_down(dsd, off, 64);
    }
    const int lane = t & 63, wid = t >> 6;
    if (lane == 0) { redA[wid] = dtd; redB[wid] = dsd; }

    // ---- stage packed sort arrays (swizzled positions) ----
    qT[SW(t)]       = ((u64)__float_as_uint(t0) << 32) | (u64)__float_as_uint(e0);
    qT[SW(t + 256)] = ((u64)__float_as_uint(t1) << 32) | (u64)__float_as_uint(e1);
    qS[SW(t)]       = ((u64)__float_as_uint(s0) << 32) | (u64)__float_as_uint(e0);
    qS[SW(t + 256)] = ((u64)__float_as_uint(s1) << 32) | (u64)__float_as_uint(e1);
    __syncthreads();

    if (t == 0) {
        float a = redA[0] + redA[1] + redA[2] + redA[3];
        float b = redB[0] + redB[1] + redB[2] + redB[3];
        diag_part_sh = 0.5f * (logf(a) + logf(b));
    }

    // ---- bitonic sort (ascending), both criteria under shared barriers ----
    for (unsigned k = 2; k <= 512; k <<= 1) {
        for (unsigned jj = k >> 1; jj >= 1; jj >>= 1) {
            __syncthreads();
            const unsigned a = ((t & ~(jj - 1)) << 1) | (t & (jj - 1));
            const unsigned b = a | jj;
            const bool up = ((a & k) == 0);
            {
                u64 va = qT[SW(a)], vb = qT[SW(b)];
                if (up ? (va > vb) : (va < vb)) { qT[SW(a)] = vb; qT[SW(b)] = va; }
            }
            {
                u64 va = qS[SW(a)], vb = qS[SW(b)];
                if (up ? (va > vb) : (va < vb)) { qS[SW(a)] = vb; qS[SW(b)] = va; }
            }
        }
    }
    __syncthreads();

    // ---- unpack: suffix-sum seed (E) + tie-run head flags (key compare) ----
    {
        const u64 v0 = qT[SW(t)],       v1 = qT[SW(t + 256)];
        sT[t]       = __uint_as_float((unsigned)v0);
        sT[t + 256] = __uint_as_float((unsigned)v1);
        const unsigned h0 = (unsigned)(v0 >> 32), h1 = (unsigned)(v1 >> 32);
        const unsigned hp1 = (unsigned)(qT[SW(t + 255)] >> 32);
        lT[t]       = (t == 0 || (unsigned)(qT[SW(t - 1)] >> 32) != h0) ? t : 0;
        lT[t + 256] = (hp1 != h1) ? (t + 256) : 0;
    }
    {
        const u64 v0 = qS[SW(t)],       v1 = qS[SW(t + 256)];
        sS[t]       = __uint_as_float((unsigned)v0);
        sS[t + 256] = __uint_as_float((unsigned)v1);
        const unsigned h0 = (unsigned)(v0 >> 32), h1 = (unsigned)(v1 >> 32);
        const unsigned hp1 = (unsigned)(qS[SW(t + 255)] >> 32);
        lS[t]       = (t == 0 || (unsigned)(qS[SW(t - 1)] >> 32) != h0) ? t : 0;
        lS[t + 256] = (hp1 != h1) ? (t + 256) : 0;
    }
    __syncthreads();

    // ---- Hillis-Steele: inclusive suffix-sum (E) + inclusive max-scan (lb),
    //      both criteria under shared barriers. 9 steps. ----
    for (int st = 1; st < 512; st <<= 1) {
        float a0 = (t + st < 512) ? sT[t + st] : 0.0f;
        float a1 = (t + 256 + st < 512) ? sT[t + 256 + st] : 0.0f;
        float b0 = (t + st < 512) ? sS[t + st] : 0.0f;
        float b1 = (t + 256 + st < 512) ? sS[t + 256 + st] : 0.0f;
        int   m0 = (t >= st) ? lT[t - st] : 0;
        int   m1 = lT[t + 256 - st];        // t+256 >= st always (st <= 256)
        int   n0 = (t >= st) ? lS[t - st] : 0;
        int   n1 = lS[t + 256 - st];
        __syncthreads();
        sT[t] += a0; sT[t + 256] += a1;
        sS[t] += b0; sS[t + 256] += b1;
        lT[t] = max(lT[t], m0); lT[t + 256] = max(lT[t + 256], m1);
        lS[t] = max(lS[t], n0); lS[t + 256] = max(lS[t + 256], n1);
        __syncthreads();
    }

    // ---- per-position log terms, block reduce, one atomic ----
    float term = logf(sT[lT[t]]) + logf(sT[lT[t + 256]])
               + logf(sS[lS[t]]) + logf(sS[lS[t + 256]]);
#pragma unroll
    for (int off = 32; off > 0; off >>= 1) term += __shfl_down(term, off, 64);
    __syncthreads();                        // redA reuse hazard
    if (lane == 0) redA[wid] = term;
    __syncthreads();
    if (t == 0) {
        float tt = redA[0] + redA[1] + redA[2] + redA[3];
        // contribution: -0.5 * (sum over j!=i of (log dt + log ds))
        atomicAdd(acc, -0.5f * tt + diag_part_sh);
    }
}

// ---------------------------------------------------------------------------
// Kernel 4: finalize scalar.
// ---------------------------------------------------------------------------
__global__ void finalize_kernel(const float* __restrict__ acc,
                                float* __restrict__ out) {
    out[0] = -acc[0] / NPAIRS;
}

extern "C" void kernel_launch(void* const* d_in, const int* in_sizes, int n_in,
                              void* d_out, int out_size, void* d_ws, size_t ws_size,
                              hipStream_t stream) {
    const float* f      = (const float*)d_in[0];  // (512, 256) fp32
    const float* labels = (const float*)d_in[1];  // (512, 9)   fp32
    float* out = (float*)d_out;                   // scalar fp32
    float* ws  = (float*)d_ws;

    float* rot  = ws;                      // 512*9
    float* tvec = rot + N * 9;             // 512*3
    float* nrm  = tvec + N * 3;            // 512
    float* acc  = nrm + N;                 // 1 (+3 pad)
    float* E    = acc + 4;                 // 512*512
    float* TD   = E + N * N;               // 512*512
    float* SD   = TD + N * N;              // 512*512

    prep_kernel<<<N, 64, 0, stream>>>(f, labels, rot, tvec, nrm, acc);
    rowdata_kernel<<<N / ITILE, 512, 0, stream>>>(f, rot, tvec, nrm, E, TD, SD, acc);
    sortdenom_kernel<<<N, 256, 0, stream>>>(E, TD, SD, acc);
    finalize_kernel<<<1, 1, 0, stream>>>(acc, out);
}